// Round 1
// baseline (121.893 us; speedup 1.0000x reference)
//
#include <hip/hip_runtime.h>

typedef float f32x4 __attribute__((ext_vector_type(4)));
typedef short bf16x8 __attribute__((ext_vector_type(8)));
typedef unsigned short u16;

// ws layout (bytes)
#define WS_PART 0         // 256 blocks * 128 f32 partial colsums = 131072 B
#define WS_GNN  131072    // 128 f32 = 512 B
#define WS_W1F  135168    // 64 frags * 1024 B = 65536
#define WS_W2F  200704    // 128 frags * 1024 B = 131072
#define WS_W3F  331776    // 64 frags * 1024 B = 65536  (end: 397312)

__device__ __forceinline__ u16 f2bf(float f) {
    union { float f; unsigned u; } v; v.f = f;
    unsigned u = v.u;
    u += 0x7FFFu + ((u >> 16) & 1u);   // round-to-nearest-even
    return (u16)(u >> 16);
}

// ---------------------------------------------------------------------------
// Kernel A: blocks 0-255: per-block column-sum partials of x (no atomics).
//           blocks 256-383: repack Wf1/Wf2/Wf3 into MFMA-fragment-ordered bf16.
// Fragment order: frag_id = nt*KS + k; elem = frag_id*512 + lane*8 + j, where
// value(lane,j) = W[k*32 + (lane>>4)*8 + j][nt*16 + (lane&15)].
// ---------------------------------------------------------------------------
__global__ __launch_bounds__(256) void k_prep(
    const float* __restrict__ x,
    const float* __restrict__ Wf1, const float* __restrict__ Wf2,
    const float* __restrict__ Wf3,
    float* __restrict__ part, u16* __restrict__ w1f, u16* __restrict__ w2f,
    u16* __restrict__ w3f, int n)
{
    int b = blockIdx.x, t = threadIdx.x;
    if (b < 256) {
        __shared__ float red[256];
        int c = t & 127, half = t >> 7;
        int rows = (n + 255) >> 8;          // ceil(n/256)
        int start = b * rows;
        int end = min(start + rows, n);
        float s = 0.f;
        for (int r = start + half; r < end; r += 2)
            s += x[r * 128 + c];
        red[t] = s;
        __syncthreads();
        if (t < 128) part[b * 128 + t] = red[t] + red[t + 128];
    } else {
        int e0 = ((b - 256) * 256 + t) * 4; // 131072 elems total
        #pragma unroll
        for (int i = 0; i < 4; ++i) {
            int e = e0 + i;
            u16* dst; const float* src; int KS, NW;
            if (e < 32768)      { dst = w1f; src = Wf1; KS = 4; NW = 256; }
            else if (e < 98304) { dst = w2f; src = Wf2; KS = 8; NW = 256; e -= 32768; }
            else                { dst = w3f; src = Wf3; KS = 8; NW = 128; e -= 98304; }
            int fi = e >> 9, within = e & 511;
            int lane = within >> 3, j = within & 7;
            int nt = fi / KS, k = fi - nt * KS;
            int nn = nt * 16 + (lane & 15);
            int kk = k * 32 + ((lane >> 4) & 3) * 8 + j;
            dst[fi * 512 + within] = f2bf(src[kk * NW + nn]);
        }
    }
}

// ---------------------------------------------------------------------------
// Kernel B: reduce colsum partials -> colmean, run the tiny GCN chain in f32.
// gnn = LN2( LN1(relu(colmean @ Wc1 + bc1)) @ Wc2 + bc2 )
// ---------------------------------------------------------------------------
__global__ __launch_bounds__(256) void k_gnn(
    const float* __restrict__ part,
    const float* __restrict__ Wc1, const float* __restrict__ bc1,
    const float* __restrict__ Wc2, const float* __restrict__ bc2,
    const float* __restrict__ g1,  const float* __restrict__ be1,
    const float* __restrict__ g2,  const float* __restrict__ be2,
    float* __restrict__ gnn, int n)
{
    int t = threadIdx.x;
    __shared__ float cm[128];
    __shared__ float hv[256];
    __shared__ float red[256];

    if (t < 128) {
        float s = 0.f;
        for (int p = 0; p < 256; ++p) s += part[p * 128 + t];
        cm[t] = s / (float)n;
    }
    __syncthreads();

    // h = relu(colmean @ Wc1 + bc1)   (t = 0..255 -> d_h columns)
    float v = bc1[t];
    for (int i = 0; i < 128; ++i) v += cm[i] * Wc1[i * 256 + t];
    v = fmaxf(v, 0.f);

    // LN over 256
    red[t] = v; __syncthreads();
    for (int s = 128; s > 0; s >>= 1) { if (t < s) red[t] += red[t + s]; __syncthreads(); }
    float mu = red[0] * (1.f / 256.f);
    __syncthreads();
    red[t] = (v - mu) * (v - mu); __syncthreads();
    for (int s = 128; s > 0; s >>= 1) { if (t < s) red[t] += red[t + s]; __syncthreads(); }
    float var = red[0] * (1.f / 256.f);
    __syncthreads();
    hv[t] = (v - mu) * rsqrtf(var + 1e-5f) * g1[t] + be1[t];
    __syncthreads();

    // h2 = hv @ Wc2 + bc2  (t < 128)
    float v2 = 0.f;
    if (t < 128) {
        v2 = bc2[t];
        for (int i = 0; i < 256; ++i) v2 += hv[i] * Wc2[i * 128 + t];
    }
    __syncthreads();

    // LN over 128
    red[t] = (t < 128) ? v2 : 0.f; __syncthreads();
    for (int s = 128; s > 0; s >>= 1) { if (t < s) red[t] += red[t + s]; __syncthreads(); }
    mu = red[0] * (1.f / 128.f);
    __syncthreads();
    red[t] = (t < 128) ? (v2 - mu) * (v2 - mu) : 0.f; __syncthreads();
    for (int s = 128; s > 0; s >>= 1) { if (t < s) red[t] += red[t + s]; __syncthreads(); }
    var = red[0] * (1.f / 128.f);
    if (t < 128) gnn[t] = (v2 - mu) * rsqrtf(var + 1e-5f) * g2[t] + be2[t];
}

// ---------------------------------------------------------------------------
// Kernel C: fused 3-layer MLP, BM=64 rows/block, 4 waves, wave w owns an
// N-slice (64 cols layers 1-2, 32 cols layer 3). bf16 MFMA, f32 accum.
// LDS tiles XOR-swizzled (group-of-8 ^ (row&7)) for conflict-free ds_read_b128.
// ---------------------------------------------------------------------------
__global__ __launch_bounds__(256, 2) void k_main(
    const float* __restrict__ x,
    const float* __restrict__ bf1, const float* __restrict__ bf2,
    const float* __restrict__ bf3,
    const u16* __restrict__ w1f, const u16* __restrict__ w2f,
    const u16* __restrict__ w3f,
    const float* __restrict__ gnn,
    float* __restrict__ out, int n)
{
    __shared__ __align__(16) u16 xs[64 * 128];
    __shared__ __align__(16) u16 h1[64 * 256];
    __shared__ __align__(16) u16 h2[64 * 256];

    int t = threadIdx.x;
    int row0 = blockIdx.x * 64;
    int w = t >> 6, lane = t & 63, lr = lane & 15, lq = lane >> 4;

    // ---- stage x tile -> xs (bf16, swizzled) ----
    #pragma unroll
    for (int it = 0; it < 4; ++it) {
        int G = t + it * 256;       // 1024 groups of 8
        int r = G >> 4, g = G & 15;
        int grow = row0 + r;
        f32x4 f0 = {0.f,0.f,0.f,0.f}, f1 = {0.f,0.f,0.f,0.f};
        if (grow < n) {
            const f32x4* p = (const f32x4*)(x + (long)grow * 128 + g * 8);
            f0 = p[0]; f1 = p[1];
        }
        u16 tmp[8];
        tmp[0]=f2bf(f0[0]); tmp[1]=f2bf(f0[1]); tmp[2]=f2bf(f0[2]); tmp[3]=f2bf(f0[3]);
        tmp[4]=f2bf(f1[0]); tmp[5]=f2bf(f1[1]); tmp[6]=f2bf(f1[2]); tmp[7]=f2bf(f1[3]);
        *(bf16x8*)(&xs[r * 128 + ((g ^ (r & 7)) * 8)]) = *(const bf16x8*)tmp;
    }
    __syncthreads();

    // ---- layer 1: h1 = relu(x @ Wf1 + bf1), M=64 N=256 K=128 ----
    {
        bf16x8 b1[4][4];
        const bf16x8* base = (const bf16x8*)w1f;
        #pragma unroll
        for (int nt = 0; nt < 4; ++nt)
            #pragma unroll
            for (int k = 0; k < 4; ++k)
                b1[nt][k] = base[(((w * 4 + nt) * 4) + k) * 64 + lane];
        float bias[4];
        #pragma unroll
        for (int nt = 0; nt < 4; ++nt) bias[nt] = bf1[w * 64 + nt * 16 + lr];

        #pragma unroll
        for (int mt = 0; mt < 4; ++mt) {
            int arow = mt * 16 + lr;
            bf16x8 a[4];
            #pragma unroll
            for (int k = 0; k < 4; ++k) {
                int g = k * 4 + lq;
                a[k] = *(const bf16x8*)(&xs[arow * 128 + ((g ^ (arow & 7)) * 8)]);
            }
            #pragma unroll
            for (int nt = 0; nt < 4; ++nt) {
                f32x4 acc = {0.f,0.f,0.f,0.f};
                #pragma unroll
                for (int k = 0; k < 4; ++k)
                    acc = __builtin_amdgcn_mfma_f32_16x16x32_bf16(a[k], b1[nt][k], acc, 0, 0, 0);
                int col = w * 64 + nt * 16 + lr;
                int cg = col >> 3, ce = col & 7;
                #pragma unroll
                for (int j = 0; j < 4; ++j) {
                    int row = mt * 16 + lq * 4 + j;
                    float v = fmaxf(acc[j] + bias[nt], 0.f);
                    h1[row * 256 + ((cg ^ (row & 7)) * 8 + ce)] = f2bf(v);
                }
            }
        }
    }
    __syncthreads();

    // ---- layer 2: h2 = relu(h1 @ Wf2 + bf2), M=64 N=256 K=256 ----
    {
        float bias[4];
        #pragma unroll
        for (int nt = 0; nt < 4; ++nt) bias[nt] = bf2[w * 64 + nt * 16 + lr];
        f32x4 acc2[4][4];
        #pragma unroll
        for (int mt = 0; mt < 4; ++mt)
            #pragma unroll
            for (int nt = 0; nt < 4; ++nt)
                acc2[mt][nt] = (f32x4){0.f,0.f,0.f,0.f};

        const bf16x8* base = (const bf16x8*)w2f;
        #pragma unroll
        for (int half = 0; half < 2; ++half) {
            bf16x8 b2[4][4];
            #pragma unroll
            for (int nt = 0; nt < 4; ++nt)
                #pragma unroll
                for (int k = 0; k < 4; ++k)
                    b2[nt][k] = base[(((w * 4 + nt) * 8) + half * 4 + k) * 64 + lane];
            #pragma unroll
            for (int mt = 0; mt < 4; ++mt) {
                int arow = mt * 16 + lr;
                bf16x8 a[4];
                #pragma unroll
                for (int k = 0; k < 4; ++k) {
                    int g = (half * 4 + k) * 4 + lq;
                    a[k] = *(const bf16x8*)(&h1[arow * 256 + ((g ^ (arow & 7)) * 8)]);
                }
                #pragma unroll
                for (int nt = 0; nt < 4; ++nt)
                    #pragma unroll
                    for (int k = 0; k < 4; ++k)
                        acc2[mt][nt] = __builtin_amdgcn_mfma_f32_16x16x32_bf16(a[k], b2[nt][k], acc2[mt][nt], 0, 0, 0);
            }
        }
        #pragma unroll
        for (int mt = 0; mt < 4; ++mt) {
            #pragma unroll
            for (int nt = 0; nt < 4; ++nt) {
                int col = w * 64 + nt * 16 + lr;
                int cg = col >> 3, ce = col & 7;
                #pragma unroll
                for (int j = 0; j < 4; ++j) {
                    int row = mt * 16 + lq * 4 + j;
                    float v = fmaxf(acc2[mt][nt][j] + bias[nt], 0.f);
                    h2[row * 256 + ((cg ^ (row & 7)) * 8 + ce)] = f2bf(v);
                }
            }
        }
    }
    __syncthreads();

    // ---- layer 3: out = (h2 @ Wf3 + bf3 + gnn) * 0.5, M=64 N=128 K=256 ----
    {
        float c3[2];
        #pragma unroll
        for (int nt = 0; nt < 2; ++nt) {
            int col = w * 32 + nt * 16 + lr;
            c3[nt] = bf3[col] + gnn[col];
        }
        bf16x8 b3[2][8];
        const bf16x8* base = (const bf16x8*)w3f;
        #pragma unroll
        for (int nt = 0; nt < 2; ++nt)
            #pragma unroll
            for (int k = 0; k < 8; ++k)
                b3[nt][k] = base[(((w * 2 + nt) * 8) + k) * 64 + lane];

        #pragma unroll
        for (int mt = 0; mt < 4; ++mt) {
            int arow = mt * 16 + lr;
            bf16x8 a[8];
            #pragma unroll
            for (int k = 0; k < 8; ++k) {
                int g = k * 4 + lq;
                a[k] = *(const bf16x8*)(&h2[arow * 256 + ((g ^ (arow & 7)) * 8)]);
            }
            #pragma unroll
            for (int nt = 0; nt < 2; ++nt) {
                f32x4 acc = {0.f,0.f,0.f,0.f};
                #pragma unroll
                for (int k = 0; k < 8; ++k)
                    acc = __builtin_amdgcn_mfma_f32_16x16x32_bf16(a[k], b3[nt][k], acc, 0, 0, 0);
                int col = w * 32 + nt * 16 + lr;
                #pragma unroll
                for (int j = 0; j < 4; ++j) {
                    int row = mt * 16 + lq * 4 + j;
                    int grow = row0 + row;
                    if (grow < n)
                        out[(long)grow * 128 + col] = (acc[j] + c3[nt]) * 0.5f;
                }
            }
        }
    }
}

extern "C" void kernel_launch(void* const* d_in, const int* in_sizes, int n_in,
                              void* d_out, int out_size, void* d_ws, size_t ws_size,
                              hipStream_t stream)
{
    const float* x   = (const float*)d_in[0];
    const float* Wc1 = (const float*)d_in[1];
    const float* bc1 = (const float*)d_in[2];
    const float* Wc2 = (const float*)d_in[3];
    const float* bc2 = (const float*)d_in[4];
    const float* g1  = (const float*)d_in[5];
    const float* be1 = (const float*)d_in[6];
    const float* g2  = (const float*)d_in[7];
    const float* be2 = (const float*)d_in[8];
    const float* Wf1 = (const float*)d_in[9];
    const float* b1  = (const float*)d_in[10];
    const float* Wf2 = (const float*)d_in[11];
    const float* b2  = (const float*)d_in[12];
    const float* Wf3 = (const float*)d_in[13];
    const float* b3  = (const float*)d_in[14];
    int n = in_sizes[0] / 128;

    char* ws = (char*)d_ws;
    float* part = (float*)(ws + WS_PART);
    float* gnn  = (float*)(ws + WS_GNN);
    u16*   w1f  = (u16*)(ws + WS_W1F);
    u16*   w2f  = (u16*)(ws + WS_W2F);
    u16*   w3f  = (u16*)(ws + WS_W3F);

    k_prep<<<384, 256, 0, stream>>>(x, Wf1, Wf2, Wf3, part, w1f, w2f, w3f, n);
    k_gnn<<<1, 256, 0, stream>>>(part, Wc1, bc1, Wc2, bc2, g1, be1, g2, be2, gnn, n);
    int nb = (n + 63) / 64;
    k_main<<<nb, 256, 0, stream>>>(x, b1, b2, b3, w1f, w2f, w3f, gnn, (float*)d_out, n);
}

// Round 2
// 92.757 us; speedup vs baseline: 1.3141x; 1.3141x over previous
//
#include <hip/hip_runtime.h>

typedef float f32x4 __attribute__((ext_vector_type(4)));
typedef short bf16x8 __attribute__((ext_vector_type(8)));
typedef unsigned short u16;

#define CS_BLOCKS 512     // colsum blocks (2/CU): 8-wave latency hiding, f32x4 loads

// ws layout (bytes)
#define WS_PART 0         // 512 blocks * 128 f32 partial colsums = 262144 B
#define WS_GNN  262144    // 128 f32 = 512 B
#define WS_W1F  262656    // 64 frags * 1024 B = 65536
#define WS_W2F  328192    // 128 frags * 1024 B = 131072
#define WS_W3F  459264    // 64 frags * 1024 B = 65536  (end: 524800)

__device__ __forceinline__ u16 f2bf(float f) {
    union { float f; unsigned u; } v; v.f = f;
    unsigned u = v.u;
    u += 0x7FFFu + ((u >> 16) & 1u);   // round-to-nearest-even
    return (u16)(u >> 16);
}

// ---------------------------------------------------------------------------
// Kernel A: blocks 0..CS_BLOCKS-1: per-block column-sum partials of x,
//           f32x4 loads (32 lanes = one 512B row, 8 rows in flight).
//           blocks CS_BLOCKS..CS_BLOCKS+127: repack Wf1/Wf2/Wf3 into
//           MFMA-fragment-ordered bf16.
// ---------------------------------------------------------------------------
__global__ __launch_bounds__(256) void k_prep(
    const float* __restrict__ x,
    const float* __restrict__ Wf1, const float* __restrict__ Wf2,
    const float* __restrict__ Wf3,
    float* __restrict__ part, u16* __restrict__ w1f, u16* __restrict__ w2f,
    u16* __restrict__ w3f, int n)
{
    int b = blockIdx.x, t = threadIdx.x;
    if (b < CS_BLOCKS) {
        __shared__ float red8[8][128];
        int col4 = t & 31, rowo = t >> 5;          // col4: 16B chunk, rowo: 0..7
        int rpb = (n + CS_BLOCKS - 1) / CS_BLOCKS;
        int start = b * rpb;
        int end = min(start + rpb, n);
        f32x4 acc = {0.f, 0.f, 0.f, 0.f};
        const f32x4* x4 = (const f32x4*)x;
        for (int r = start + rowo; r < end; r += 8)
            acc += x4[r * 32 + col4];
        *(f32x4*)&red8[rowo][col4 * 4] = acc;
        __syncthreads();
        if (t < 128) {
            float s = red8[0][t] + red8[1][t] + red8[2][t] + red8[3][t]
                    + red8[4][t] + red8[5][t] + red8[6][t] + red8[7][t];
            part[b * 128 + t] = s;
        }
    } else {
        int e0 = ((b - CS_BLOCKS) * 256 + t) * 4; // 131072 elems total
        #pragma unroll
        for (int i = 0; i < 4; ++i) {
            int e = e0 + i;
            u16* dst; const float* src; int KS, NW;
            if (e < 32768)      { dst = w1f; src = Wf1; KS = 4; NW = 256; }
            else if (e < 98304) { dst = w2f; src = Wf2; KS = 8; NW = 256; e -= 32768; }
            else                { dst = w3f; src = Wf3; KS = 8; NW = 128; e -= 98304; }
            int fi = e >> 9, within = e & 511;
            int lane = within >> 3, j = within & 7;
            int nt = fi / KS, k = fi - nt * KS;
            int nn = nt * 16 + (lane & 15);
            int kk = k * 32 + ((lane >> 4) & 3) * 8 + j;
            dst[fi * 512 + within] = f2bf(src[kk * NW + nn]);
        }
    }
}

// ---------------------------------------------------------------------------
// Kernel B: reduce colsum partials -> colmean (vectorized), then the tiny
// GCN chain in f32: gnn = LN2( LN1(relu(colmean@Wc1+bc1)) @ Wc2 + bc2 )
// ---------------------------------------------------------------------------
__global__ __launch_bounds__(256) void k_gnn(
    const float* __restrict__ part,
    const float* __restrict__ Wc1, const float* __restrict__ bc1,
    const float* __restrict__ Wc2, const float* __restrict__ bc2,
    const float* __restrict__ g1,  const float* __restrict__ be1,
    const float* __restrict__ g2,  const float* __restrict__ be2,
    float* __restrict__ gnn, int n)
{
    int t = threadIdx.x;
    __shared__ float cm[128];
    __shared__ float hv[256];
    __shared__ float red[256];
    __shared__ float red8[8][128];

    // vectorized partial reduce: 512 partials of 128 cols
    {
        int col4 = t & 31, rowo = t >> 5;
        f32x4 acc = {0.f, 0.f, 0.f, 0.f};
        const f32x4* p4 = (const f32x4*)part;
        for (int p = rowo; p < CS_BLOCKS; p += 8)
            acc += p4[p * 32 + col4];
        *(f32x4*)&red8[rowo][col4 * 4] = acc;
        __syncthreads();
        if (t < 128) {
            float s = red8[0][t] + red8[1][t] + red8[2][t] + red8[3][t]
                    + red8[4][t] + red8[5][t] + red8[6][t] + red8[7][t];
            cm[t] = s / (float)n;
        }
    }
    __syncthreads();

    // h = relu(colmean @ Wc1 + bc1)   (t = 0..255 -> d_h columns)
    float v = bc1[t];
    for (int i = 0; i < 128; ++i) v += cm[i] * Wc1[i * 256 + t];
    v = fmaxf(v, 0.f);

    // LN over 256
    red[t] = v; __syncthreads();
    for (int s = 128; s > 0; s >>= 1) { if (t < s) red[t] += red[t + s]; __syncthreads(); }
    float mu = red[0] * (1.f / 256.f);
    __syncthreads();
    red[t] = (v - mu) * (v - mu); __syncthreads();
    for (int s = 128; s > 0; s >>= 1) { if (t < s) red[t] += red[t + s]; __syncthreads(); }
    float var = red[0] * (1.f / 256.f);
    __syncthreads();
    hv[t] = (v - mu) * rsqrtf(var + 1e-5f) * g1[t] + be1[t];
    __syncthreads();

    // h2 = hv @ Wc2 + bc2  (t < 128)
    float v2 = 0.f;
    if (t < 128) {
        v2 = bc2[t];
        for (int i = 0; i < 256; ++i) v2 += hv[i] * Wc2[i * 128 + t];
    }
    __syncthreads();

    // LN over 128
    red[t] = (t < 128) ? v2 : 0.f; __syncthreads();
    for (int s = 128; s > 0; s >>= 1) { if (t < s) red[t] += red[t + s]; __syncthreads(); }
    mu = red[0] * (1.f / 128.f);
    __syncthreads();
    red[t] = (t < 128) ? (v2 - mu) * (v2 - mu) : 0.f; __syncthreads();
    for (int s = 128; s > 0; s >>= 1) { if (t < s) red[t] += red[t + s]; __syncthreads(); }
    var = red[0] * (1.f / 128.f);
    if (t < 128) gnn[t] = (v2 - mu) * rsqrtf(var + 1e-5f) * g2[t] + be2[t];
}

// ---------------------------------------------------------------------------
// Kernel C: fused 3-layer MLP, BM=64 rows/block, 4 waves, wave w owns an
// N-slice (64 cols layers 1-2, 32 cols layer 3). bf16 MFMA, f32 accum.
// LDS tiles XOR-swizzled (group-of-8 ^ (row&7)) for conflict-free ds_read_b128.
// ---------------------------------------------------------------------------
__global__ __launch_bounds__(256, 2) void k_main(
    const float* __restrict__ x,
    const float* __restrict__ bf1, const float* __restrict__ bf2,
    const float* __restrict__ bf3,
    const u16* __restrict__ w1f, const u16* __restrict__ w2f,
    const u16* __restrict__ w3f,
    const float* __restrict__ gnn,
    float* __restrict__ out, int n)
{
    __shared__ __align__(16) u16 xs[64 * 128];
    __shared__ __align__(16) u16 h1[64 * 256];
    __shared__ __align__(16) u16 h2[64 * 256];

    int t = threadIdx.x;
    int row0 = blockIdx.x * 64;
    int w = t >> 6, lane = t & 63, lr = lane & 15, lq = lane >> 4;

    // ---- stage x tile -> xs (bf16, swizzled) ----
    #pragma unroll
    for (int it = 0; it < 4; ++it) {
        int G = t + it * 256;       // 1024 groups of 8
        int r = G >> 4, g = G & 15;
        int grow = row0 + r;
        f32x4 f0 = {0.f,0.f,0.f,0.f}, f1 = {0.f,0.f,0.f,0.f};
        if (grow < n) {
            const f32x4* p = (const f32x4*)(x + (long)grow * 128 + g * 8);
            f0 = p[0]; f1 = p[1];
        }
        u16 tmp[8];
        tmp[0]=f2bf(f0[0]); tmp[1]=f2bf(f0[1]); tmp[2]=f2bf(f0[2]); tmp[3]=f2bf(f0[3]);
        tmp[4]=f2bf(f1[0]); tmp[5]=f2bf(f1[1]); tmp[6]=f2bf(f1[2]); tmp[7]=f2bf(f1[3]);
        *(bf16x8*)(&xs[r * 128 + ((g ^ (r & 7)) * 8)]) = *(const bf16x8*)tmp;
    }
    __syncthreads();

    // ---- layer 1: h1 = relu(x @ Wf1 + bf1), M=64 N=256 K=128 ----
    {
        bf16x8 b1[4][4];
        const bf16x8* base = (const bf16x8*)w1f;
        #pragma unroll
        for (int nt = 0; nt < 4; ++nt)
            #pragma unroll
            for (int k = 0; k < 4; ++k)
                b1[nt][k] = base[(((w * 4 + nt) * 4) + k) * 64 + lane];
        float bias[4];
        #pragma unroll
        for (int nt = 0; nt < 4; ++nt) bias[nt] = bf1[w * 64 + nt * 16 + lr];

        #pragma unroll
        for (int mt = 0; mt < 4; ++mt) {
            int arow = mt * 16 + lr;
            bf16x8 a[4];
            #pragma unroll
            for (int k = 0; k < 4; ++k) {
                int g = k * 4 + lq;
                a[k] = *(const bf16x8*)(&xs[arow * 128 + ((g ^ (arow & 7)) * 8)]);
            }
            #pragma unroll
            for (int nt = 0; nt < 4; ++nt) {
                f32x4 acc = {0.f,0.f,0.f,0.f};
                #pragma unroll
                for (int k = 0; k < 4; ++k)
                    acc = __builtin_amdgcn_mfma_f32_16x16x32_bf16(a[k], b1[nt][k], acc, 0, 0, 0);
                int col = w * 64 + nt * 16 + lr;
                int cg = col >> 3, ce = col & 7;
                #pragma unroll
                for (int j = 0; j < 4; ++j) {
                    int row = mt * 16 + lq * 4 + j;
                    float v = fmaxf(acc[j] + bias[nt], 0.f);
                    h1[row * 256 + ((cg ^ (row & 7)) * 8 + ce)] = f2bf(v);
                }
            }
        }
    }
    __syncthreads();

    // ---- layer 2: h2 = relu(h1 @ Wf2 + bf2), M=64 N=256 K=256 ----
    {
        float bias[4];
        #pragma unroll
        for (int nt = 0; nt < 4; ++nt) bias[nt] = bf2[w * 64 + nt * 16 + lr];
        f32x4 acc2[4][4];
        #pragma unroll
        for (int mt = 0; mt < 4; ++mt)
            #pragma unroll
            for (int nt = 0; nt < 4; ++nt)
                acc2[mt][nt] = (f32x4){0.f,0.f,0.f,0.f};

        const bf16x8* base = (const bf16x8*)w2f;
        #pragma unroll
        for (int half = 0; half < 2; ++half) {
            bf16x8 b2[4][4];
            #pragma unroll
            for (int nt = 0; nt < 4; ++nt)
                #pragma unroll
                for (int k = 0; k < 4; ++k)
                    b2[nt][k] = base[(((w * 4 + nt) * 8) + half * 4 + k) * 64 + lane];
            #pragma unroll
            for (int mt = 0; mt < 4; ++mt) {
                int arow = mt * 16 + lr;
                bf16x8 a[4];
                #pragma unroll
                for (int k = 0; k < 4; ++k) {
                    int g = (half * 4 + k) * 4 + lq;
                    a[k] = *(const bf16x8*)(&h1[arow * 256 + ((g ^ (arow & 7)) * 8)]);
                }
                #pragma unroll
                for (int nt = 0; nt < 4; ++nt)
                    #pragma unroll
                    for (int k = 0; k < 4; ++k)
                        acc2[mt][nt] = __builtin_amdgcn_mfma_f32_16x16x32_bf16(a[k], b2[nt][k], acc2[mt][nt], 0, 0, 0);
            }
        }
        #pragma unroll
        for (int mt = 0; mt < 4; ++mt) {
            #pragma unroll
            for (int nt = 0; nt < 4; ++nt) {
                int col = w * 64 + nt * 16 + lr;
                int cg = col >> 3, ce = col & 7;
                #pragma unroll
                for (int j = 0; j < 4; ++j) {
                    int row = mt * 16 + lq * 4 + j;
                    float v = fmaxf(acc2[mt][nt][j] + bias[nt], 0.f);
                    h2[row * 256 + ((cg ^ (row & 7)) * 8 + ce)] = f2bf(v);
                }
            }
        }
    }
    __syncthreads();

    // ---- layer 3: out = (h2 @ Wf3 + bf3 + gnn) * 0.5, M=64 N=128 K=256 ----
    {
        float c3[2];
        #pragma unroll
        for (int nt = 0; nt < 2; ++nt) {
            int col = w * 32 + nt * 16 + lr;
            c3[nt] = bf3[col] + gnn[col];
        }
        bf16x8 b3[2][8];
        const bf16x8* base = (const bf16x8*)w3f;
        #pragma unroll
        for (int nt = 0; nt < 2; ++nt)
            #pragma unroll
            for (int k = 0; k < 8; ++k)
                b3[nt][k] = base[(((w * 2 + nt) * 8) + k) * 64 + lane];

        #pragma unroll
        for (int mt = 0; mt < 4; ++mt) {
            int arow = mt * 16 + lr;
            bf16x8 a[8];
            #pragma unroll
            for (int k = 0; k < 8; ++k) {
                int g = k * 4 + lq;
                a[k] = *(const bf16x8*)(&h2[arow * 256 + ((g ^ (arow & 7)) * 8)]);
            }
            #pragma unroll
            for (int nt = 0; nt < 2; ++nt) {
                f32x4 acc = {0.f,0.f,0.f,0.f};
                #pragma unroll
                for (int k = 0; k < 8; ++k)
                    acc = __builtin_amdgcn_mfma_f32_16x16x32_bf16(a[k], b3[nt][k], acc, 0, 0, 0);
                int col = w * 32 + nt * 16 + lr;
                #pragma unroll
                for (int j = 0; j < 4; ++j) {
                    int row = mt * 16 + lq * 4 + j;
                    int grow = row0 + row;
                    if (grow < n)
                        out[(long)grow * 128 + col] = (acc[j] + c3[nt]) * 0.5f;
                }
            }
        }
    }
}

extern "C" void kernel_launch(void* const* d_in, const int* in_sizes, int n_in,
                              void* d_out, int out_size, void* d_ws, size_t ws_size,
                              hipStream_t stream)
{
    const float* x   = (const float*)d_in[0];
    const float* Wc1 = (const float*)d_in[1];
    const float* bc1 = (const float*)d_in[2];
    const float* Wc2 = (const float*)d_in[3];
    const float* bc2 = (const float*)d_in[4];
    const float* g1  = (const float*)d_in[5];
    const float* be1 = (const float*)d_in[6];
    const float* g2  = (const float*)d_in[7];
    const float* be2 = (const float*)d_in[8];
    const float* Wf1 = (const float*)d_in[9];
    const float* b1  = (const float*)d_in[10];
    const float* Wf2 = (const float*)d_in[11];
    const float* b2  = (const float*)d_in[12];
    const float* Wf3 = (const float*)d_in[13];
    const float* b3  = (const float*)d_in[14];
    int n = in_sizes[0] / 128;

    char* ws = (char*)d_ws;
    float* part = (float*)(ws + WS_PART);
    float* gnn  = (float*)(ws + WS_GNN);
    u16*   w1f  = (u16*)(ws + WS_W1F);
    u16*   w2f  = (u16*)(ws + WS_W2F);
    u16*   w3f  = (u16*)(ws + WS_W3F);

    k_prep<<<CS_BLOCKS + 128, 256, 0, stream>>>(x, Wf1, Wf2, Wf3, part, w1f, w2f, w3f, n);
    k_gnn<<<1, 256, 0, stream>>>(part, Wc1, bc1, Wc2, bc2, g1, be1, g2, be2, gnn, n);
    int nb = (n + 63) / 64;
    k_main<<<nb, 256, 0, stream>>>(x, b1, b2, b3, w1f, w2f, w3f, gnn, (float*)d_out, n);
}